// Round 1
// baseline (1386.471 us; speedup 1.0000x reference)
//
#include <hip/hip_runtime.h>

#define N_PTS 16384
#define DIMS  128
#define NQ    16384
#define NV    64

#define QT 64        // queries per block
#define PT 64        // points per LDS tile
#define LSTRIDE 132  // padded row stride (floats): breaks power-of-2 bank pattern, keeps 16B align

// ---- p_sq precompute: one wave per row, float2 per lane, butterfly reduce ----
__global__ __launch_bounds__(256) void psq_kernel(const float* __restrict__ points,
                                                  float* __restrict__ p_sq) {
    int row  = blockIdx.x * 4 + (threadIdx.x >> 6);
    int lane = threadIdx.x & 63;
    float2 v = *(const float2*)(points + row * DIMS + lane * 2);
    float s = v.x * v.x + v.y * v.y;
#pragma unroll
    for (int off = 32; off > 0; off >>= 1) s += __shfl_xor(s, off, 64);
    if (lane == 0) p_sq[row] = s;
}

// ---- main: streaming argmin over point tiles + fused value gather ----
__global__ __launch_bounds__(256, 2) void nn_kernel(const float* __restrict__ points,
                                                    const float* __restrict__ values,
                                                    const float* __restrict__ pointsq,
                                                    const float* __restrict__ p_sq,
                                                    float* __restrict__ out) {
    __shared__ float lq[QT * LSTRIDE];   // [q][k], padded
    __shared__ float lp[PT * LSTRIDE];   // [p][k], padded
    __shared__ float lps[PT];
    __shared__ float red_val[QT][16];
    __shared__ int   red_idx[QT][16];
    __shared__ int   nn_idx[QT];

    const int tid   = threadIdx.x;
    const int tx    = tid & 15;   // point-group owner: points {tx, tx+16, tx+32, tx+48}
    const int ty    = tid >> 4;   // query-group owner: queries {ty, ty+16, ty+32, ty+48}
    const int qbase = blockIdx.x * QT;

    // stage query tile once: thread (ql=tid>>2, quad=tid&3) copies row chunks, coalesced 64B/4-lanes
    {
        int ql = tid >> 2, quad = tid & 3;
        const float4* src = (const float4*)(pointsq + (size_t)(qbase + ql) * DIMS);
#pragma unroll
        for (int j = 0; j < 8; ++j) {
            float4 v = src[quad + 4 * j];
            *(float4*)(lq + ql * LSTRIDE + (quad + 4 * j) * 4) = v;
        }
    }

    float minv[4];
    int   mini[4];
#pragma unroll
    for (int qi = 0; qi < 4; ++qi) { minv[qi] = 3.4e38f; mini[qi] = 0; }

    for (int tile = 0; tile < N_PTS / PT; ++tile) {
        __syncthreads();   // protect lp from previous iteration's readers
        {
            int pl = tid >> 2, quad = tid & 3;
            const float4* src = (const float4*)(points + (size_t)(tile * PT + pl) * DIMS);
#pragma unroll
            for (int j = 0; j < 8; ++j) {
                float4 v = src[quad + 4 * j];
                *(float4*)(lp + pl * LSTRIDE + (quad + 4 * j) * 4) = v;
            }
            if (tid < PT) lps[tid] = p_sq[tile * PT + tid];
        }
        __syncthreads();

        float acc[4][4];
#pragma unroll
        for (int qi = 0; qi < 4; ++qi)
#pragma unroll
            for (int pi = 0; pi < 4; ++pi) acc[qi][pi] = 0.f;

        for (int kc = 0; kc < DIMS / 4; ++kc) {
            float4 aq[4], ap[4];
#pragma unroll
            for (int qi = 0; qi < 4; ++qi)
                aq[qi] = *(const float4*)(lq + (ty + 16 * qi) * LSTRIDE + kc * 4);
#pragma unroll
            for (int pi = 0; pi < 4; ++pi)
                ap[pi] = *(const float4*)(lp + (tx + 16 * pi) * LSTRIDE + kc * 4);
#pragma unroll
            for (int qi = 0; qi < 4; ++qi)
#pragma unroll
                for (int pi = 0; pi < 4; ++pi) {
                    acc[qi][pi] += aq[qi].x * ap[pi].x;
                    acc[qi][pi] += aq[qi].y * ap[pi].y;
                    acc[qi][pi] += aq[qi].z * ap[pi].z;
                    acc[qi][pi] += aq[qi].w * ap[pi].w;
                }
        }

        // running argmin; pi ascending => index ascending => strict < keeps lowest index
#pragma unroll
        for (int qi = 0; qi < 4; ++qi)
#pragma unroll
            for (int pi = 0; pi < 4; ++pi) {
                float score = lps[tx + 16 * pi] - 2.f * acc[qi][pi];
                int   idx   = tile * PT + tx + 16 * pi;
                if (score < minv[qi]) { minv[qi] = score; mini[qi] = idx; }
            }
    }

    // cross-thread (tx) argmin reduction per query
    __syncthreads();
#pragma unroll
    for (int qi = 0; qi < 4; ++qi) {
        red_val[ty + 16 * qi][tx] = minv[qi];
        red_idx[ty + 16 * qi][tx] = mini[qi];
    }
    __syncthreads();
    if (tid < QT) {
        float bv = red_val[tid][0];
        int   bi = red_idx[tid][0];
#pragma unroll
        for (int t = 1; t < 16; ++t) {
            float v = red_val[tid][t];
            int   i = red_idx[tid][t];
            if (v < bv || (v == bv && i < bi)) { bv = v; bi = i; }
        }
        nn_idx[tid] = bi;
    }
    __syncthreads();

    // fused gather: 64 queries x 64 values, thread copies 16 floats
    {
        int ql = tid >> 2, quad = tid & 3;
        const float4* src = (const float4*)(values + (size_t)nn_idx[ql] * NV);
        float4*       dst = (float4*)(out + (size_t)(qbase + ql) * NV);
#pragma unroll
        for (int j = 0; j < 4; ++j) dst[quad * 4 + j] = src[quad * 4 + j];
    }
}

extern "C" void kernel_launch(void* const* d_in, const int* in_sizes, int n_in,
                              void* d_out, int out_size, void* d_ws, size_t ws_size,
                              hipStream_t stream) {
    const float* points  = (const float*)d_in[0];  // [16384,128]
    const float* values  = (const float*)d_in[1];  // [16384,64]
    const float* pointsq = (const float*)d_in[2];  // [16384,128]
    float*       out     = (float*)d_out;          // [16384,64]
    float*       p_sq    = (float*)d_ws;           // 16384 floats

    psq_kernel<<<N_PTS / 4, 256, 0, stream>>>(points, p_sq);
    nn_kernel<<<NQ / QT, 256, 0, stream>>>(points, values, pointsq, p_sq, out);
}

// Round 2
// 641.419 us; speedup vs baseline: 2.1616x; 2.1616x over previous
//
#include <hip/hip_runtime.h>

#define N_PTS 16384
#define DIMS  128
#define NQ    16384
#define NV    64
#define KTOT  512   // 4 fp16 products: (a1+a2)(b1+b2)
#define BK    64

typedef __attribute__((ext_vector_type(8)))  _Float16 half8;
typedef __attribute__((ext_vector_type(16))) float    f32x16;

// ---------------- p_sq: one wave per row, fp32 exact ----------------
__global__ __launch_bounds__(256) void psq_kernel(const float* __restrict__ points,
                                                  float* __restrict__ p_sq) {
    int row  = blockIdx.x * 4 + (threadIdx.x >> 6);
    int lane = threadIdx.x & 63;
    float2 v = *(const float2*)(points + row * DIMS + lane * 2);
    float s = v.x * v.x + v.y * v.y;
#pragma unroll
    for (int off = 32; off > 0; off >>= 1) s += __shfl_xor(s, off, 64);
    if (lane == 0) p_sq[row] = s;
}

// ---------------- fp32 -> (hi,lo) fp16 split ----------------
// mode 0 (queries): [h1 | h1 | h2 | h2]   mode 1 (points): [h1 | h2 | h1 | h2]
__global__ __launch_bounds__(256) void split_kernel(const float* __restrict__ in,
                                                    _Float16* __restrict__ out, int mode) {
    int idx = blockIdx.x * 256 + threadIdx.x;   // N*D elements
    int r = idx >> 7, c = idx & 127;
    float x = in[idx];
    _Float16 h1 = (_Float16)x;
    float r1 = x - (float)h1;
    _Float16 h2 = (_Float16)r1;
    _Float16* o = out + (size_t)r * KTOT + c;
    if (mode == 0) { o[0] = h1; o[128] = h1; o[256] = h2; o[384] = h2; }
    else           { o[0] = h1; o[128] = h2; o[256] = h1; o[384] = h2; }
}

__device__ __forceinline__ unsigned int f2sortable(float f) {
    unsigned int b = __float_as_uint(f);
    return (b & 0x80000000u) ? ~b : (b | 0x80000000u);
}

__device__ __forceinline__ void gload16(const void* g, void* l) {
    __builtin_amdgcn_global_load_lds((const __attribute__((address_space(1))) void*)g,
                                     (__attribute__((address_space(3))) void*)l, 16, 0, 0);
}

// ---------------- main: 128x256 tile fp16 MFMA GEMM + streaming argmin ----------------
__global__ __launch_bounds__(256) void nn_mfma(const _Float16* __restrict__ A,   // [16384][512] queries
                                               const _Float16* __restrict__ B,   // [16384][512] points
                                               const float* __restrict__ p_sq,
                                               unsigned long long* __restrict__ keys) {
    __shared__ _Float16 As[128 * BK];   // 16 KB, row-major swizzled 16B chunks
    __shared__ _Float16 Bs[256 * BK];   // 32 KB

    // supertile swizzle: 8x8 block groups for L2 locality (mtiles=128, ntiles=64)
    int bid = blockIdx.x;
    int g  = bid >> 6;
    int gm = g >> 3, gn = g & 7;
    int lm = (bid >> 3) & 7, ln = bid & 7;
    int mtile = gm * 8 + lm;            // 0..127
    int ntile = gn * 8 + ln;            // 0..63

    const int tid = threadIdx.x;
    const int w   = tid >> 6;           // wave 0..3
    const int l   = tid & 63;
    const int wq  = w >> 1;             // wave tile: 64 rows x 128 cols
    const int wp  = w & 1;

    const int srow  = l >> 3;           // staging: 8 rows per wave-issue
    const int sslot = l & 7;
    const size_t arow0 = (size_t)mtile * 128;
    const size_t brow0 = (size_t)ntile * 256;

    const int m = l & 31;               // MFMA lane coords
    const int h = l >> 5;

    f32x16 acc[2][4] = {};              // 2 qi x 4 pi tiles of 32x32

    for (int kk = 0; kk < KTOT; kk += BK) {
        __syncthreads();
        // stage A: 128 rows x 64 fp16 (16 KB), 4 issues; chunk g stored at slot s = g ^ ((r&31)>>2)
#pragma unroll
        for (int i = 0; i < 4; ++i) {
            int r = i * 32 + w * 8 + srow;
            int gch = sslot ^ ((r >> 2) & 7);
            gload16(A + (arow0 + r) * KTOT + kk + gch * 8, As + (size_t)(i * 32 + w * 8) * BK);
        }
        // stage B: 256 rows (32 KB), 8 issues
#pragma unroll
        for (int i = 0; i < 8; ++i) {
            int r = i * 32 + w * 8 + srow;
            int gch = sslot ^ ((r >> 2) & 7);
            gload16(B + (brow0 + r) * KTOT + kk + gch * 8, Bs + (size_t)(i * 32 + w * 8) * BK);
        }
        __syncthreads();

#pragma unroll
        for (int ks = 0; ks < 4; ++ks) {       // 4 MFMA-K steps of 16 per BK=64
            int gp   = ks * 2 + h;             // chunk index within row
            int slot = gp ^ ((m >> 2) & 7);    // bank-balanced read
            half8 a[2], b[4];
#pragma unroll
            for (int qi = 0; qi < 2; ++qi)
                a[qi] = *(const half8*)(As + (size_t)(wq * 64 + qi * 32 + m) * BK + slot * 8);
#pragma unroll
            for (int pi = 0; pi < 4; ++pi)
                b[pi] = *(const half8*)(Bs + (size_t)(wp * 128 + pi * 32 + m) * BK + slot * 8);
#pragma unroll
            for (int qi = 0; qi < 2; ++qi)
#pragma unroll
                for (int pi = 0; pi < 4; ++pi)
                    acc[qi][pi] = __builtin_amdgcn_mfma_f32_32x32x16_f16(a[qi], b[pi], acc[qi][pi], 0, 0, 0);
        }
    }

    // ---- epilogue: score = p_sq - 2*dot, per-row argmin, one atomic per row ----
    float psq[4];
#pragma unroll
    for (int pi = 0; pi < 4; ++pi)
        psq[pi] = p_sq[ntile * 256 + wp * 128 + pi * 32 + m];

#pragma unroll
    for (int qi = 0; qi < 2; ++qi)
#pragma unroll
        for (int reg = 0; reg < 16; ++reg) {
            // 32x32 C/D layout: row=(reg&3)+8*(reg>>2)+4*(lane>>5), col=lane&31
            int row = mtile * 128 + wq * 64 + qi * 32 + (reg & 3) + 8 * (reg >> 2) + 4 * h;
            float best = 0.f; int bidx = 0;
#pragma unroll
            for (int pi = 0; pi < 4; ++pi) {
                float s   = psq[pi] - 2.0f * acc[qi][pi][reg];
                int   idx = ntile * 256 + wp * 128 + pi * 32 + m;
                if (pi == 0 || s < best) { best = s; bidx = idx; }  // pi asc => idx asc, strict <
            }
            // butterfly argmin across the 32-lane half (cols), lowest-idx tie-break
#pragma unroll
            for (int off = 1; off < 32; off <<= 1) {
                float ov = __shfl_xor(best, off, 64);
                int   oi = __shfl_xor(bidx, off, 64);
                if (ov < best || (ov == best && oi < bidx)) { best = ov; bidx = oi; }
            }
            if (m == 0) {
                unsigned long long key =
                    ((unsigned long long)f2sortable(best) << 32) | (unsigned int)bidx;
                atomicMin(&keys[row], key);
            }
        }
}

// ---------------- gather: out[q] = values[key[q] & 0xffffffff] ----------------
__global__ __launch_bounds__(256) void gather_kernel(const unsigned long long* __restrict__ keys,
                                                     const float* __restrict__ values,
                                                     float* __restrict__ out) {
    int tid = threadIdx.x;
    int q = blockIdx.x * 16 + (tid >> 4);
    int c = tid & 15;
    int idx = (int)(keys[q] & 0xFFFFFFFFull);
    const float4* src = (const float4*)(values + (size_t)idx * NV);
    float4*       dst = (float4*)(out + (size_t)q * NV);
    dst[c] = src[c];
}

// ================= fallback (round-1 fp32 LDS kernel) =================
#define QT 64
#define PT 64
#define LSTRIDE 132
__global__ __launch_bounds__(256, 2) void nn_kernel(const float* __restrict__ points,
                                                    const float* __restrict__ values,
                                                    const float* __restrict__ pointsq,
                                                    const float* __restrict__ p_sq,
                                                    float* __restrict__ out) {
    __shared__ float lq[QT * LSTRIDE];
    __shared__ float lp[PT * LSTRIDE];
    __shared__ float lps[PT];
    __shared__ float red_val[QT][16];
    __shared__ int   red_idx[QT][16];
    __shared__ int   nn_idx[QT];

    const int tid = threadIdx.x;
    const int tx = tid & 15, ty = tid >> 4;
    const int qbase = blockIdx.x * QT;
    {
        int ql = tid >> 2, quad = tid & 3;
        const float4* src = (const float4*)(pointsq + (size_t)(qbase + ql) * DIMS);
#pragma unroll
        for (int j = 0; j < 8; ++j)
            *(float4*)(lq + ql * LSTRIDE + (quad + 4 * j) * 4) = src[quad + 4 * j];
    }
    float minv[4]; int mini[4];
#pragma unroll
    for (int qi = 0; qi < 4; ++qi) { minv[qi] = 3.4e38f; mini[qi] = 0; }
    for (int tile = 0; tile < N_PTS / PT; ++tile) {
        __syncthreads();
        {
            int pl = tid >> 2, quad = tid & 3;
            const float4* src = (const float4*)(points + (size_t)(tile * PT + pl) * DIMS);
#pragma unroll
            for (int j = 0; j < 8; ++j)
                *(float4*)(lp + pl * LSTRIDE + (quad + 4 * j) * 4) = src[quad + 4 * j];
            if (tid < PT) lps[tid] = p_sq[tile * PT + tid];
        }
        __syncthreads();
        float accl[4][4];
#pragma unroll
        for (int qi = 0; qi < 4; ++qi)
#pragma unroll
            for (int pi = 0; pi < 4; ++pi) accl[qi][pi] = 0.f;
        for (int kc = 0; kc < DIMS / 4; ++kc) {
            float4 aq[4], ap[4];
#pragma unroll
            for (int qi = 0; qi < 4; ++qi) aq[qi] = *(const float4*)(lq + (ty + 16 * qi) * LSTRIDE + kc * 4);
#pragma unroll
            for (int pi = 0; pi < 4; ++pi) ap[pi] = *(const float4*)(lp + (tx + 16 * pi) * LSTRIDE + kc * 4);
#pragma unroll
            for (int qi = 0; qi < 4; ++qi)
#pragma unroll
                for (int pi = 0; pi < 4; ++pi) {
                    accl[qi][pi] += aq[qi].x * ap[pi].x; accl[qi][pi] += aq[qi].y * ap[pi].y;
                    accl[qi][pi] += aq[qi].z * ap[pi].z; accl[qi][pi] += aq[qi].w * ap[pi].w;
                }
        }
#pragma unroll
        for (int qi = 0; qi < 4; ++qi)
#pragma unroll
            for (int pi = 0; pi < 4; ++pi) {
                float score = lps[tx + 16 * pi] - 2.f * accl[qi][pi];
                int idx = tile * PT + tx + 16 * pi;
                if (score < minv[qi]) { minv[qi] = score; mini[qi] = idx; }
            }
    }
    __syncthreads();
#pragma unroll
    for (int qi = 0; qi < 4; ++qi) { red_val[ty + 16 * qi][tx] = minv[qi]; red_idx[ty + 16 * qi][tx] = mini[qi]; }
    __syncthreads();
    if (tid < QT) {
        float bv = red_val[tid][0]; int bi = red_idx[tid][0];
#pragma unroll
        for (int t = 1; t < 16; ++t) {
            float v = red_val[tid][t]; int i = red_idx[tid][t];
            if (v < bv || (v == bv && i < bi)) { bv = v; bi = i; }
        }
        nn_idx[tid] = bi;
    }
    __syncthreads();
    {
        int ql = tid >> 2, quad = tid & 3;
        const float4* src = (const float4*)(values + (size_t)nn_idx[ql] * NV);
        float4* dst = (float4*)(out + (size_t)(qbase + ql) * NV);
#pragma unroll
        for (int j = 0; j < 4; ++j) dst[quad * 4 + j] = src[quad * 4 + j];
    }
}

extern "C" void kernel_launch(void* const* d_in, const int* in_sizes, int n_in,
                              void* d_out, int out_size, void* d_ws, size_t ws_size,
                              hipStream_t stream) {
    const float* points  = (const float*)d_in[0];
    const float* values  = (const float*)d_in[1];
    const float* pointsq = (const float*)d_in[2];
    float*       out     = (float*)d_out;

    // ws layout: keys (128 KB) | p_sq (64 KB) | A' (16 MB) | B' (16 MB)
    const size_t OFF_KEYS = 0;
    const size_t OFF_PSQ  = 131072;
    const size_t OFF_A    = 196608;
    const size_t OFF_B    = OFF_A + (size_t)NQ * KTOT * 2;
    const size_t NEEDED   = OFF_B + (size_t)N_PTS * KTOT * 2;

    if (ws_size >= NEEDED) {
        unsigned long long* keys = (unsigned long long*)((char*)d_ws + OFF_KEYS);
        float*    p_sq = (float*)((char*)d_ws + OFF_PSQ);
        _Float16* Aq   = (_Float16*)((char*)d_ws + OFF_A);
        _Float16* Bp   = (_Float16*)((char*)d_ws + OFF_B);

        hipMemsetAsync(keys, 0xFF, (size_t)NQ * 8, stream);
        psq_kernel<<<N_PTS / 4, 256, 0, stream>>>(points, p_sq);
        split_kernel<<<NQ * DIMS / 256, 256, 0, stream>>>(pointsq, Aq, 0);
        split_kernel<<<N_PTS * DIMS / 256, 256, 0, stream>>>(points, Bp, 1);
        nn_mfma<<<(NQ / 128) * (N_PTS / 256), 256, 0, stream>>>(Aq, Bp, p_sq, keys);
        gather_kernel<<<NQ / 16, 256, 0, stream>>>(keys, values, out);
    } else {
        float* p_sq = (float*)d_ws;
        psq_kernel<<<N_PTS / 4, 256, 0, stream>>>(points, p_sq);
        nn_kernel<<<NQ / QT, 256, 0, stream>>>(points, values, pointsq, p_sq, out);
    }
}

// Round 3
// 560.200 us; speedup vs baseline: 2.4750x; 1.1450x over previous
//
#include <hip/hip_runtime.h>

#define N_PTS 16384
#define DIMS  128
#define NQ    16384
#define NV    64
#define KTOT  384   // 3 fp16 products: a1b1 + a1b2 + a2b1  (a2b2 dropped, ~3e-5 abs)
#define BK    64
#define BM    64    // block tile M (queries)
#define BN    256   // block tile N (points)

typedef __attribute__((ext_vector_type(8)))  _Float16 half8;
typedef __attribute__((ext_vector_type(4)))  _Float16 half4;
typedef __attribute__((ext_vector_type(16))) float    f32x16;

// ---------------- p_sq: one wave per row, fp32 exact ----------------
__global__ __launch_bounds__(256) void psq_kernel(const float* __restrict__ points,
                                                  float* __restrict__ p_sq) {
    int row  = blockIdx.x * 4 + (threadIdx.x >> 6);
    int lane = threadIdx.x & 63;
    float2 v = *(const float2*)(points + row * DIMS + lane * 2);
    float s = v.x * v.x + v.y * v.y;
#pragma unroll
    for (int off = 32; off > 0; off >>= 1) s += __shfl_xor(s, off, 64);
    if (lane == 0) p_sq[row] = s;
}

// ---------------- fp32 -> (hi,lo) fp16 split, vectorized ----------------
// mode 0 (queries): [h1 | h1 | h2]   mode 1 (points): [h1 | h2 | h1]
__global__ __launch_bounds__(256) void split_kernel(const float* __restrict__ in,
                                                    _Float16* __restrict__ out, int mode) {
    int t = blockIdx.x * 256 + threadIdx.x;     // one float4 per thread
    int idx4 = t * 4;
    int r = idx4 >> 7, c = idx4 & 127;
    float4 x = *(const float4*)(in + idx4);
    half4 h1, h2;
    {
        float xs[4] = {x.x, x.y, x.z, x.w};
#pragma unroll
        for (int j = 0; j < 4; ++j) {
            _Float16 a = (_Float16)xs[j];
            h1[j] = a;
            h2[j] = (_Float16)(xs[j] - (float)a);
        }
    }
    _Float16* o = out + (size_t)r * KTOT + c;
    if (mode == 0) { *(half4*)o = h1; *(half4*)(o + 128) = h1; *(half4*)(o + 256) = h2; }
    else           { *(half4*)o = h1; *(half4*)(o + 128) = h2; *(half4*)(o + 256) = h1; }
}

__device__ __forceinline__ unsigned int f2sortable(float f) {
    unsigned int b = __float_as_uint(f);
    return (b & 0x80000000u) ? ~b : (b | 0x80000000u);
}

__device__ __forceinline__ void gload16(const void* g, void* l) {
    __builtin_amdgcn_global_load_lds((const __attribute__((address_space(1))) void*)g,
                                     (__attribute__((address_space(3))) void*)l, 16, 0, 0);
}

// -------- main: 64x256 block tile (2 waves), fp16 MFMA + streaming argmin --------
// LDS 40 KB -> 4 blocks/CU = 4 independent barrier domains (latency hiding).
__global__ __launch_bounds__(128, 2) void nn_mfma(const _Float16* __restrict__ A,   // [NQ][KTOT]
                                                  const _Float16* __restrict__ B,   // [N_PTS][KTOT]
                                                  const float* __restrict__ p_sq,
                                                  unsigned long long* __restrict__ keys) {
    __shared__ _Float16 As[BM * BK];   //  8 KB
    __shared__ _Float16 Bs[BN * BK];   // 32 KB

    // 256 mtiles x 64 ntiles; 8x8 supertile swizzle for L2 locality
    int bid = blockIdx.x;
    int g  = bid >> 6;                  // 0..255
    int gm = g >> 3, gn = g & 7;        // 32 x 8 groups
    int lm = (bid >> 3) & 7, ln = bid & 7;
    int mtile = gm * 8 + lm;            // 0..255
    int ntile = gn * 8 + ln;            // 0..63

    const int tid = threadIdx.x;
    const int w   = tid >> 6;           // wave 0..1 (N-split: wave covers cols w*128..+128)
    const int l   = tid & 63;
    const int m   = l & 31;             // MFMA lane coords
    const int h   = l >> 5;
    const int srow  = l >> 3;           // staging row-within-issue
    const int sslot = l & 7;            // staging slot

    const size_t arow0 = (size_t)mtile * BM;
    const size_t brow0 = (size_t)ntile * BN;

    f32x16 acc[2][4] = {};              // 2 qi x 4 pi tiles of 32x32

    for (int kk = 0; kk < KTOT; kk += BK) {
        __syncthreads();
        // A: 64 rows x 64 fp16 = 8 issues; wave w does j = w*4+i
#pragma unroll
        for (int i = 0; i < 4; ++i) {
            int j = w * 4 + i;
            int r = j * 8 + srow;
            int gch = sslot ^ ((r >> 1) & 7);
            gload16(A + (arow0 + r) * KTOT + kk + gch * 8, As + (size_t)j * 512);
        }
        // B: 256 rows = 32 issues; wave w does j = w*16+i (stages its own read half)
#pragma unroll
        for (int i = 0; i < 16; ++i) {
            int j = w * 16 + i;
            int r = j * 8 + srow;
            int gch = sslot ^ ((r >> 1) & 7);
            gload16(B + (brow0 + r) * KTOT + kk + gch * 8, Bs + (size_t)j * 512);
        }
        __syncthreads();

#pragma unroll
        for (int ks = 0; ks < 4; ++ks) {       // 4 MFMA-K steps of 16
            int gp = ks * 2 + h;               // 16B chunk index within row
            half8 a[2], b[4];
#pragma unroll
            for (int qi = 0; qi < 2; ++qi) {
                int row  = qi * 32 + m;
                int slot = gp ^ ((row >> 1) & 7);
                a[qi] = *(const half8*)(As + (size_t)row * BK + slot * 8);
            }
#pragma unroll
            for (int pi = 0; pi < 4; ++pi) {
                int row  = w * 128 + pi * 32 + m;
                int slot = gp ^ ((row >> 1) & 7);
                b[pi] = *(const half8*)(Bs + (size_t)row * BK + slot * 8);
            }
#pragma unroll
            for (int qi = 0; qi < 2; ++qi)
#pragma unroll
                for (int pi = 0; pi < 4; ++pi)
                    acc[qi][pi] = __builtin_amdgcn_mfma_f32_32x32x16_f16(a[qi], b[pi], acc[qi][pi], 0, 0, 0);
        }
    }

    // ---- epilogue: score = p_sq - 2*dot, per-row argmin, one atomic per row ----
    float psq[4];
#pragma unroll
    for (int pi = 0; pi < 4; ++pi)
        psq[pi] = p_sq[ntile * BN + w * 128 + pi * 32 + m];

#pragma unroll
    for (int qi = 0; qi < 2; ++qi)
#pragma unroll
        for (int reg = 0; reg < 16; ++reg) {
            // 32x32 C/D layout: row=(reg&3)+8*(reg>>2)+4*(lane>>5), col=lane&31
            int row = mtile * BM + qi * 32 + (reg & 3) + 8 * (reg >> 2) + 4 * h;
            float best = 0.f; int bidx = 0;
#pragma unroll
            for (int pi = 0; pi < 4; ++pi) {
                float s   = psq[pi] - 2.0f * acc[qi][pi][reg];
                int   idx = ntile * BN + w * 128 + pi * 32 + m;
                if (pi == 0 || s < best) { best = s; bidx = idx; }   // pi asc => idx asc
            }
#pragma unroll
            for (int off = 1; off < 32; off <<= 1) {                  // 32-lane butterfly
                float ov = __shfl_xor(best, off, 64);
                int   oi = __shfl_xor(bidx, off, 64);
                if (ov < best || (ov == best && oi < bidx)) { best = ov; bidx = oi; }
            }
            if (m == 0) {
                unsigned long long key =
                    ((unsigned long long)f2sortable(best) << 32) | (unsigned int)bidx;
                atomicMin(&keys[row], key);
            }
        }
}

// ---------------- gather: out[q] = values[key[q] & 0xffffffff] ----------------
__global__ __launch_bounds__(256) void gather_kernel(const unsigned long long* __restrict__ keys,
                                                     const float* __restrict__ values,
                                                     float* __restrict__ out) {
    int tid = threadIdx.x;
    int q = blockIdx.x * 16 + (tid >> 4);
    int c = tid & 15;
    int idx = (int)(keys[q] & 0xFFFFFFFFull);
    const float4* src = (const float4*)(values + (size_t)idx * NV);
    float4*       dst = (float4*)(out + (size_t)q * NV);
    dst[c] = src[c];
}

// ================= fallback (round-1 fp32 LDS kernel) =================
#define QT 64
#define PT 64
#define LSTRIDE 132
__global__ __launch_bounds__(256, 2) void nn_kernel(const float* __restrict__ points,
                                                    const float* __restrict__ values,
                                                    const float* __restrict__ pointsq,
                                                    const float* __restrict__ p_sq,
                                                    float* __restrict__ out) {
    __shared__ float lq[QT * LSTRIDE];
    __shared__ float lp[PT * LSTRIDE];
    __shared__ float lps[PT];
    __shared__ float red_val[QT][16];
    __shared__ int   red_idx[QT][16];
    __shared__ int   nn_idx[QT];

    const int tid = threadIdx.x;
    const int tx = tid & 15, ty = tid >> 4;
    const int qbase = blockIdx.x * QT;
    {
        int ql = tid >> 2, quad = tid & 3;
        const float4* src = (const float4*)(pointsq + (size_t)(qbase + ql) * DIMS);
#pragma unroll
        for (int j = 0; j < 8; ++j)
            *(float4*)(lq + ql * LSTRIDE + (quad + 4 * j) * 4) = src[quad + 4 * j];
    }
    float minv[4]; int mini[4];
#pragma unroll
    for (int qi = 0; qi < 4; ++qi) { minv[qi] = 3.4e38f; mini[qi] = 0; }
    for (int tile = 0; tile < N_PTS / PT; ++tile) {
        __syncthreads();
        {
            int pl = tid >> 2, quad = tid & 3;
            const float4* src = (const float4*)(points + (size_t)(tile * PT + pl) * DIMS);
#pragma unroll
            for (int j = 0; j < 8; ++j)
                *(float4*)(lp + pl * LSTRIDE + (quad + 4 * j) * 4) = src[quad + 4 * j];
            if (tid < PT) lps[tid] = p_sq[tile * PT + tid];
        }
        __syncthreads();
        float accl[4][4];
#pragma unroll
        for (int qi = 0; qi < 4; ++qi)
#pragma unroll
            for (int pi = 0; pi < 4; ++pi) accl[qi][pi] = 0.f;
        for (int kc = 0; kc < DIMS / 4; ++kc) {
            float4 aq[4], ap[4];
#pragma unroll
            for (int qi = 0; qi < 4; ++qi) aq[qi] = *(const float4*)(lq + (ty + 16 * qi) * LSTRIDE + kc * 4);
#pragma unroll
            for (int pi = 0; pi < 4; ++pi) ap[pi] = *(const float4*)(lp + (tx + 16 * pi) * LSTRIDE + kc * 4);
#pragma unroll
            for (int qi = 0; qi < 4; ++qi)
#pragma unroll
                for (int pi = 0; pi < 4; ++pi) {
                    accl[qi][pi] += aq[qi].x * ap[pi].x; accl[qi][pi] += aq[qi].y * ap[pi].y;
                    accl[qi][pi] += aq[qi].z * ap[pi].z; accl[qi][pi] += aq[qi].w * ap[pi].w;
                }
        }
#pragma unroll
        for (int qi = 0; qi < 4; ++qi)
#pragma unroll
            for (int pi = 0; pi < 4; ++pi) {
                float score = lps[tx + 16 * pi] - 2.f * accl[qi][pi];
                int idx = tile * PT + tx + 16 * pi;
                if (score < minv[qi]) { minv[qi] = score; mini[qi] = idx; }
            }
    }
    __syncthreads();
#pragma unroll
    for (int qi = 0; qi < 4; ++qi) { red_val[ty + 16 * qi][tx] = minv[qi]; red_idx[ty + 16 * qi][tx] = mini[qi]; }
    __syncthreads();
    if (tid < QT) {
        float bv = red_val[tid][0]; int bi = red_idx[tid][0];
#pragma unroll
        for (int t = 1; t < 16; ++t) {
            float v = red_val[tid][t]; int i = red_idx[tid][t];
            if (v < bv || (v == bv && i < bi)) { bv = v; bi = i; }
        }
        nn_idx[tid] = bi;
    }
    __syncthreads();
    {
        int ql = tid >> 2, quad = tid & 3;
        const float4* src = (const float4*)(values + (size_t)nn_idx[ql] * NV);
        float4* dst = (float4*)(out + (size_t)qbase * NV + (size_t)ql * NV);
#pragma unroll
        for (int j = 0; j < 4; ++j) dst[quad * 4 + j] = src[quad * 4 + j];
    }
}

extern "C" void kernel_launch(void* const* d_in, const int* in_sizes, int n_in,
                              void* d_out, int out_size, void* d_ws, size_t ws_size,
                              hipStream_t stream) {
    const float* points  = (const float*)d_in[0];
    const float* values  = (const float*)d_in[1];
    const float* pointsq = (const float*)d_in[2];
    float*       out     = (float*)d_out;

    // ws layout: keys (128 KB) | p_sq (64 KB) | A' (12 MB) | B' (12 MB)
    const size_t OFF_KEYS = 0;
    const size_t OFF_PSQ  = 131072;
    const size_t OFF_A    = 196608;
    const size_t OFF_B    = OFF_A + (size_t)NQ * KTOT * 2;
    const size_t NEEDED   = OFF_B + (size_t)N_PTS * KTOT * 2;

    if (ws_size >= NEEDED) {
        unsigned long long* keys = (unsigned long long*)((char*)d_ws + OFF_KEYS);
        float*    p_sq = (float*)((char*)d_ws + OFF_PSQ);
        _Float16* Aq   = (_Float16*)((char*)d_ws + OFF_A);
        _Float16* Bp   = (_Float16*)((char*)d_ws + OFF_B);

        hipMemsetAsync(keys, 0xFF, (size_t)NQ * 8, stream);
        psq_kernel<<<N_PTS / 4, 256, 0, stream>>>(points, p_sq);
        split_kernel<<<NQ * DIMS / 1024, 256, 0, stream>>>(pointsq, Aq, 0);
        split_kernel<<<N_PTS * DIMS / 1024, 256, 0, stream>>>(points, Bp, 1);
        nn_mfma<<<(NQ / BM) * (N_PTS / BN), 128, 0, stream>>>(Aq, Bp, p_sq, keys);
        gather_kernel<<<NQ / 16, 256, 0, stream>>>(keys, values, out);
    } else {
        float* p_sq = (float*)d_ws;
        psq_kernel<<<N_PTS / 4, 256, 0, stream>>>(points, p_sq);
        nn_kernel<<<NQ / QT, 256, 0, stream>>>(points, values, pointsq, p_sq, out);
    }
}